// Round 2
// baseline (362.639 us; speedup 1.0000x reference)
//
#include <hip/hip_runtime.h>
#include <stdint.h>
#include <stddef.h>

#define NB 4
#define NC 320
#define NH 128
#define NW 240
#define ND 49
#define HW (NH * NW)          // 30720
#define CC 32                 // channels per chunk
#define NCHUNK (NC / CC)      // 10
#define XMAX 128              // LDS X window capacity (cols)
#define YMAX 160              // LDS Y window capacity (cols)
#define BUFSZ ((XMAX + YMAX) * CC)   // shorts per buffer = 9216

typedef float f32x4 __attribute__((ext_vector_type(4)));
typedef short s16x8 __attribute__((ext_vector_type(8)));

__device__ __forceinline__ uint32_t bf16r(float f) {
  uint32_t u = __builtin_bit_cast(uint32_t, f);
  return (u + 0x7FFFu + ((u >> 16) & 1u)) >> 16;  // RNE f32 -> bf16
}
// c8-block swizzle keyed on (relative) w: conflict-free b128 reads/writes.
__device__ __forceinline__ int swz(int w) { return (w ^ (w >> 2)) & 3; }

// Each block handles one (b,h) row and HALF of the 15 wi-tiles.
// HALF=0: tiles 0..7,  X cols [0,128),   Y cols [0,128)
// HALF=1: tiles 8..14, X cols [128,240), Y cols [80,240)
template <int HALF>
__device__ __forceinline__ void cv_body(const float* __restrict__ xrow,
                                        const float* __restrict__ yrow,
                                        float* __restrict__ orow,
                                        short* lds, const int tid) {
  constexpr int WT0   = HALF ? 8   : 0;
  constexpr int XW0   = HALF ? 128 : 0;
  constexpr int XCOLS = HALF ? 112 : 128;
  constexpr int YW0   = HALF ? 80  : 0;
  constexpr int YCOLS = HALF ? 160 : 128;
  constexpr int NW4X  = XCOLS / 4;
  constexpr int NW4Y  = YCOLS / 4;

  const int wave = tid >> 6;
  const int l = tid & 63;
  const int m = l & 15;   // fragment row/col
  const int q = l >> 4;   // k-group

  // Main staging unit: (array, w4, c8) -> 8 x dwordx4 loads, 4 x b128 writes.
  int u_arr, u_w4, u_c8;
  if (tid < XCOLS) { u_arr = 0; u_w4 = tid % NW4X; u_c8 = tid / NW4X; }
  else             { const int v = tid - XCOLS; u_arr = 1; u_w4 = v % NW4Y; u_c8 = v / NW4Y; }
  const float* u_src = (u_arr ? yrow : xrow) + (u_arr ? YW0 : XW0) + u_w4 * 4;
  const int u_lds = u_arr ? XMAX * CC : 0;

  // HALF=1 has 272 units (112 X + 160 Y) over 256 threads: 16 extra Y units
  // (c8=3, w4=24..39) spread 4-per-wave over threads with (tid&15)==0.
  const bool has_e = (HALF == 1) && ((tid & 15) == 0);
  const int e_w4 = 24 + (tid >> 4);
  const float* e_src = yrow + YW0 + e_w4 * 4;

  f32x4 acc[2][4] = {};
  f32x4 val[8];
  f32x4 val2[8];

  auto load_units = [&](int chunk) {
    const float* p = u_src + (size_t)(chunk * CC + u_c8 * 8) * HW;
#pragma unroll
    for (int j = 0; j < 8; ++j) val[j] = *(const f32x4*)(p + (size_t)j * HW);
    if (has_e) {
      const float* p2 = e_src + (size_t)(chunk * CC + 24) * HW;
#pragma unroll
      for (int j = 0; j < 8; ++j) val2[j] = *(const f32x4*)(p2 + (size_t)j * HW);
    }
  };

  auto write_units = [&](int buf) {
    {
      short* base = lds + buf * BUFSZ + u_lds;
#pragma unroll
      for (int idx = 0; idx < 4; ++idx) {
        const int ww = (idx + u_w4) & 3;   // rotate so bank bit4 varies per instr
        const int w = u_w4 * 4 + ww;
        s16x8 s;
#pragma unroll
        for (int j = 0; j < 8; ++j) s[j] = (short)bf16r(val[j][ww]);
        *(s16x8*)&base[w * CC + ((u_c8 ^ swz(w)) * 8)] = s;
      }
    }
    if (has_e) {
      short* base = lds + buf * BUFSZ + XMAX * CC;
#pragma unroll
      for (int idx = 0; idx < 4; ++idx) {
        const int ww = (idx + e_w4) & 3;
        const int w = e_w4 * 4 + ww;
        s16x8 s;
#pragma unroll
        for (int j = 0; j < 8; ++j) s[j] = (short)bf16r(val2[j][ww]);
        *(s16x8*)&base[w * CC + ((3 ^ swz(w)) * 8)] = s;
      }
    }
  };

  auto compute = [&](int buf) {
    const short* bx = lds + buf * BUFSZ;
    const short* by = lds + buf * BUFSZ + XMAX * CC;
#pragma unroll
    for (int i = 0; i < 2; ++i) {
      const int wt = WT0 + wave * 2 + i;
      if (HALF == 1 && wt > 14) continue;       // half1 wave3 has 1 tile
      const int war = wt * 16 + m - XW0;
      const s16x8 a = *(const s16x8*)&bx[war * CC + ((q ^ swz(war)) * 8)];
#pragma unroll
      for (int ss = 0; ss < 4; ++ss) {
        const int st = wt - 3 + ss;
        if (HALF == 1 || st >= 0) {             // half1: st >= 5 always
          const int wbr = st * 16 + m - YW0;
          const s16x8 bb = *(const s16x8*)&by[wbr * CC + ((q ^ swz(wbr)) * 8)];
          acc[i][ss] = __builtin_amdgcn_mfma_f32_16x16x32_bf16(a, bb, acc[i][ss], 0, 0, 0);
        }
      }
    }
  };

  load_units(0);
  write_units(0);
  __syncthreads();
  for (int k = 0; k < NCHUNK; ++k) {
    if (k + 1 < NCHUNK) load_units(k + 1);      // issue early (prefetch)
    compute(k & 1);
    if (k + 1 < NCHUNK) write_units((k + 1) & 1);
    __syncthreads();
  }

  // Epilogue: d = wi - wj; virtual tiles (st<0, HALF=0 only) emit the w<d zeros.
#pragma unroll
  for (int i = 0; i < 2; ++i) {
    const int wt = WT0 + wave * 2 + i;
    if (HALF == 1 && wt > 14) continue;
#pragma unroll
    for (int ss = 0; ss < 4; ++ss) {
      const int st = wt - 3 + ss;
      const int wj = st * 16 + m;
#pragma unroll
      for (int r = 0; r < 4; ++r) {
        const int wi = wt * 16 + q * 4 + r;     // C/D: row = (lane>>4)*4 + reg
        const int d = wi - wj;
        if (d >= 0 && d < ND) {
          const float v = (st >= 0) ? acc[i][ss][r] : 0.0f;
          orow[(size_t)d * (NB * HW) + wi] = v;
        }
      }
    }
  }
}

__global__ __launch_bounds__(256, 4) void cv_kernel(const float* __restrict__ X,
                                                    const float* __restrict__ Y,
                                                    float* __restrict__ O) {
  __shared__ short lds[2 * BUFSZ];  // 36864 B -> 4 blocks/CU
  const int tid = threadIdx.x;
  const int bid = blockIdx.x;
  // XCD-chunked swizzle (1024 = 8*128, bijective): both halves of a row land
  // on the same XCD so the shared Y[80,128) window hits L2.
  const int logical = (bid & 7) * 128 + (bid >> 3);
  const int row = logical >> 1;   // 0..511 = b*128 + h
  const int half = logical & 1;
  const int b = row >> 7, h = row & 127;
  const float* xrow = X + (size_t)b * NC * HW + (size_t)h * NW;
  const float* yrow = Y + (size_t)b * NC * HW + (size_t)h * NW;
  float* orow = O + ((size_t)b * NH + h) * NW;
  if (half == 0) cv_body<0>(xrow, yrow, orow, lds, tid);
  else           cv_body<1>(xrow, yrow, orow, lds, tid);
}

extern "C" void kernel_launch(void* const* d_in, const int* in_sizes, int n_in,
                              void* d_out, int out_size, void* d_ws, size_t ws_size,
                              hipStream_t stream) {
  const float* x = (const float*)d_in[0];
  const float* y = (const float*)d_in[1];
  float* out = (float*)d_out;
  cv_kernel<<<dim3(1024), dim3(256), 0, stream>>>(x, y, out);
}

// Round 3
// 83.141 us; speedup vs baseline: 4.3617x; 4.3617x over previous
//
#include <hip/hip_runtime.h>
#include <stdint.h>
#include <stddef.h>

#define NB 4
#define NC 320
#define NH 128
#define NW 240
#define ND 49
#define HW (NH * NW)          // 30720
#define CC 32                 // channels per chunk
#define NCHUNK (NC / CC)      // 10
#define XMAX 128              // LDS X window capacity (cols)
#define YMAX 160              // LDS Y window capacity (cols)
#define BUFSZ ((XMAX + YMAX) * CC)   // shorts per buffer = 9216 (18.4 KB)

typedef float f32x4 __attribute__((ext_vector_type(4)));
typedef short s16x8 __attribute__((ext_vector_type(8)));

__device__ __forceinline__ uint32_t bf16r(float f) {
  uint32_t u = __builtin_bit_cast(uint32_t, f);
  return (u + 0x7FFFu + ((u >> 16) & 1u)) >> 16;  // RNE f32 -> bf16
}
// c8-block swizzle keyed on (relative) w: conflict-free b128 reads/writes.
__device__ __forceinline__ int swz(int w) { return (w ^ (w >> 2)) & 3; }

// Each block handles one (b,h) row and HALF of the 15 wi-tiles.
// HALF=0: tiles 0..7,  X cols [0,128),   Y cols [0,128)
// HALF=1: tiles 8..14, X cols [128,240), Y cols [80,240)
template <int HALF>
__device__ __forceinline__ void cv_body(const float* __restrict__ xrow,
                                        const float* __restrict__ yrow,
                                        float* __restrict__ orow,
                                        short* lds, const int tid) {
  constexpr int WT0   = HALF ? 8   : 0;
  constexpr int XW0   = HALF ? 128 : 0;
  constexpr int XCOLS = HALF ? 112 : 128;
  constexpr int YW0   = HALF ? 80  : 0;
  constexpr int YCOLS = HALF ? 160 : 128;
  constexpr int NW4X  = XCOLS / 4;
  constexpr int NW4Y  = YCOLS / 4;

  const int wave = tid >> 6;
  const int l = tid & 63;
  const int m = l & 15;   // fragment row/col
  const int q = l >> 4;   // k-group

  // Staging unit: (array, w4, c8) -> 8 x dwordx4 loads, 4 x b128 writes.
  // FUSED load->convert->write: no register live-range across the barrier,
  // so nothing for the allocator to spill (round-2 failure mode).
  int u_arr, u_w4, u_c8;
  if (tid < XCOLS) { u_arr = 0; u_w4 = tid % NW4X; u_c8 = tid / NW4X; }
  else             { const int v = tid - XCOLS; u_arr = 1; u_w4 = v % NW4Y; u_c8 = v / NW4Y; }
  const float* u_src = (u_arr ? yrow : xrow) + (u_arr ? YW0 : XW0) + u_w4 * 4;
  const int u_lds = u_arr ? XMAX * CC : 0;

  // HALF=1 has 272 units (112 X + 160 Y) over 256 threads: 16 extra Y units
  // (c8=3, w4=24..39) spread 4-per-wave over threads with (tid&15)==0.
  const bool has_e = (HALF == 1) && ((tid & 15) == 0);
  const int e_w4 = 24 + (tid >> 4);
  const float* e_src = yrow + YW0 + e_w4 * 4;

  f32x4 acc[2][4] = {};

  auto stage = [&](int buf, int chunk) {
    {
      const float* p = u_src + (size_t)(chunk * CC + u_c8 * 8) * HW;
      f32x4 val[8];
#pragma unroll
      for (int j = 0; j < 8; ++j) val[j] = *(const f32x4*)(p + (size_t)j * HW);
      short* base = lds + buf * BUFSZ + u_lds;
#pragma unroll
      for (int idx = 0; idx < 4; ++idx) {
        const int ww = (idx + u_w4) & 3;   // rotate store order: bank-uniform
        const int w = u_w4 * 4 + ww;
        s16x8 s;
#pragma unroll
        for (int j = 0; j < 8; ++j) s[j] = (short)bf16r(val[j][ww]);
        *(s16x8*)&base[w * CC + ((u_c8 ^ swz(w)) * 8)] = s;
      }
    }
    if (has_e) {
      const float* p2 = e_src + (size_t)(chunk * CC + 24) * HW;
      f32x4 val2[8];
#pragma unroll
      for (int j = 0; j < 8; ++j) val2[j] = *(const f32x4*)(p2 + (size_t)j * HW);
      short* base = lds + buf * BUFSZ + XMAX * CC;
#pragma unroll
      for (int idx = 0; idx < 4; ++idx) {
        const int ww = (idx + e_w4) & 3;
        const int w = e_w4 * 4 + ww;
        s16x8 s;
#pragma unroll
        for (int j = 0; j < 8; ++j) s[j] = (short)bf16r(val2[j][ww]);
        *(s16x8*)&base[w * CC + ((3 ^ swz(w)) * 8)] = s;
      }
    }
  };

  auto compute = [&](int buf) {
    const short* bx = lds + buf * BUFSZ;
    const short* by = lds + buf * BUFSZ + XMAX * CC;
#pragma unroll
    for (int i = 0; i < 2; ++i) {
      const int wt = WT0 + wave * 2 + i;
      if (HALF == 1 && wt > 14) continue;       // half1 wave3 has 1 tile
      const int war = wt * 16 + m - XW0;
      const s16x8 a = *(const s16x8*)&bx[war * CC + ((q ^ swz(war)) * 8)];
#pragma unroll
      for (int ss = 0; ss < 4; ++ss) {
        const int st = wt - 3 + ss;
        if (HALF == 1 || st >= 0) {             // half1: st >= 5 always
          const int wbr = st * 16 + m - YW0;
          const s16x8 bb = *(const s16x8*)&by[wbr * CC + ((q ^ swz(wbr)) * 8)];
          acc[i][ss] = __builtin_amdgcn_mfma_f32_16x16x32_bf16(a, bb, acc[i][ss], 0, 0, 0);
        }
      }
    }
  };

  stage(0, 0);
  __syncthreads();
  for (int k = 0; k < NCHUNK; ++k) {
    // Stage chunk k+1 into the other buffer in the SAME inter-barrier region
    // as compute(k): loads issue first in program order; MFMAs below are
    // independent, so the scheduler can hide HBM latency under them. Even if
    // it sinks the loads, 4 blocks/CU give cross-block overlap.
    if (k + 1 < NCHUNK) stage((k + 1) & 1, k + 1);
    compute(k & 1);
    __syncthreads();   // separates compute(k) reads from iter-k+2 writes
  }

  // Epilogue: d = wi - wj; virtual tiles (st<0, HALF=0 only) emit the w<d zeros.
#pragma unroll
  for (int i = 0; i < 2; ++i) {
    const int wt = WT0 + wave * 2 + i;
    if (HALF == 1 && wt > 14) continue;
#pragma unroll
    for (int ss = 0; ss < 4; ++ss) {
      const int st = wt - 3 + ss;
      const int wj = st * 16 + m;
#pragma unroll
      for (int r = 0; r < 4; ++r) {
        const int wi = wt * 16 + q * 4 + r;     // C/D: row = (lane>>4)*4 + reg
        const int d = wi - wj;
        if (d >= 0 && d < ND) {
          const float v = (st >= 0) ? acc[i][ss][r] : 0.0f;
          orow[(size_t)d * (NB * HW) + wi] = v;
        }
      }
    }
  }
}

__global__ __launch_bounds__(256)
__attribute__((amdgpu_waves_per_eu(4, 4)))   // pin budget: 512/4 = 128 VGPRs, no spill-for-occupancy
void cv_kernel(const float* __restrict__ X,
               const float* __restrict__ Y,
               float* __restrict__ O) {
  __shared__ short lds[2 * BUFSZ];  // 36864 B -> 4 blocks/CU
  const int tid = threadIdx.x;
  const int bid = blockIdx.x;
  // XCD-chunked swizzle (1024 = 8*128, bijective): both halves of a row land
  // on the same XCD so the shared Y[80,128) window hits L2.
  const int logical = (bid & 7) * 128 + (bid >> 3);
  const int row = logical >> 1;   // 0..511 = b*128 + h
  const int half = logical & 1;
  const int b = row >> 7, h = row & 127;
  const float* xrow = X + (size_t)b * NC * HW + (size_t)h * NW;
  const float* yrow = Y + (size_t)b * NC * HW + (size_t)h * NW;
  float* orow = O + ((size_t)b * NH + h) * NW;
  if (half == 0) cv_body<0>(xrow, yrow, orow, lds, tid);
  else           cv_body<1>(xrow, yrow, orow, lds, tid);
}

extern "C" void kernel_launch(void* const* d_in, const int* in_sizes, int n_in,
                              void* d_out, int out_size, void* d_ws, size_t ws_size,
                              hipStream_t stream) {
  const float* x = (const float*)d_in[0];
  const float* y = (const float*)d_in[1];
  float* out = (float*)d_out;
  cv_kernel<<<dim3(1024), dim3(256), 0, stream>>>(x, y, out);
}